// Round 2
// baseline (5537.716 us; speedup 1.0000x reference)
//
#include <hip/hip_runtime.h>
#include <math.h>

// Problem constants
#define B     32
#define IC    512
#define OC    256
#define HW    32     // input spatial
#define OHW   64     // output spatial

// Fused formulation:
//   z[oc, 2u+pm, 2v+pn] = sum_ic sum_{k,l in [0,3)} x[ic, u-1+k, v-1+l] * G[pm,pn][oc,ic,k,l]
//   G[pm,pn][oc,ic,k,l] = g2d[2k+1-pm, 2l+1-pn]
//   g2d[s,t] = sum_{i,j} (w[oc,ic,i,j]*gain) * f2[s-2+i, t-2+j]   (f2 idx valid in [0,4))
//   f2[a][b] = f1[a]*f1[b]/16, f1 = {1,3,3,1}; gain = 1/sqrt(512*9)
// then out = leaky_relu(z + bias, 0.2) * sqrt(2)
//
// G stored in d_ws as G[ic][p][oc][kl]  (p = pm*2+pn, kl = k*3+l)
// size = 512*4*256*9 floats = 18,874,368 bytes  (requires ws_size >= 19MB)

__global__ void wtrans_kernel(const float* __restrict__ w, float* __restrict__ G) {
    int t = blockIdx.x * blockDim.x + threadIdx.x;
    if (t >= OC * IC) return;
    int oc = t / IC, ic = t % IC;

    const float gain = 1.0f / sqrtf((float)(IC * 9));
    float wl[3][3];
    const float* wp = w + ((size_t)oc * IC + ic) * 9;
#pragma unroll
    for (int i = 0; i < 3; ++i)
#pragma unroll
        for (int j = 0; j < 3; ++j)
            wl[i][j] = wp[i * 3 + j] * gain;

    const float f1[4] = {1.f, 3.f, 3.f, 1.f};
    float g2[6][6];
#pragma unroll
    for (int s = 0; s < 6; ++s) {
#pragma unroll
        for (int tt = 0; tt < 6; ++tt) {
            float acc = 0.f;
#pragma unroll
            for (int i = 0; i < 3; ++i) {
#pragma unroll
                for (int j = 0; j < 3; ++j) {
                    int a = s - 2 + i, b = tt - 2 + j;
                    if (a >= 0 && a < 4 && b >= 0 && b < 4)
                        acc += wl[i][j] * f1[a] * f1[b] * 0.0625f;
                }
            }
            g2[s][tt] = acc;
        }
    }

#pragma unroll
    for (int pm = 0; pm < 2; ++pm)
#pragma unroll
        for (int pn = 0; pn < 2; ++pn)
#pragma unroll
            for (int k = 0; k < 3; ++k)
#pragma unroll
                for (int l = 0; l < 3; ++l) {
                    int p = pm * 2 + pn;
                    size_t idx = (((size_t)ic * 4 + p) * OC + oc) * 9 + k * 3 + l;
                    G[idx] = g2[2 * k + 1 - pm][2 * l + 1 - pn];
                }
}

#define OCT 8    // oc per block
#define UT  16   // (u,v) tile per block: 16x16
#define ICB 8    // input channels staged per iteration

// block: 512 threads = 8 oc-lanes (wave each) x 64 spatial threads (each 2x2 points)
__global__ __launch_bounds__(512) void conv_kernel(const float* __restrict__ x,
                                                   const float* __restrict__ G,
                                                   const float* __restrict__ bias,
                                                   float* __restrict__ out) {
    int bid = blockIdx.x;
    int sptile = bid & 3;          // 2x2 tiles of 16x16 (u,v)
    int b      = (bid >> 2) & 31;
    int octile = bid >> 7;         // 0..31  (slowest: concurrent blocks share G slice)
    int u0 = (sptile >> 1) * UT;
    int v0 = (sptile & 1) * UT;

    int tid = threadIdx.x;
    int ocl = tid >> 6;            // 0..7 (one wave per oc)
    int st  = tid & 63;
    int ut  = st >> 3;             // 0..7
    int vt  = st & 7;              // 0..7
    int oc  = octile * OCT + ocl;

    __shared__ float xs[ICB][18][18];          // halo'd x tile: 10368 B
    __shared__ float gs[ICB][4][OCT][9];       // G slice:        9216 B

    float acc[4][2][2];
#pragma unroll
    for (int p = 0; p < 4; ++p)
#pragma unroll
        for (int a = 0; a < 2; ++a)
#pragma unroll
            for (int c = 0; c < 2; ++c) acc[p][a][c] = 0.f;

    for (int ic0 = 0; ic0 < IC; ic0 += ICB) {
        // stage x halo tile: ICB * 18 * 18 = 2592 elements
        for (int i = tid; i < ICB * 324; i += 512) {
            int icl = i / 324;
            int r = i % 324;
            int hh = r / 18, ww = r % 18;
            int h = u0 - 1 + hh, wv = v0 - 1 + ww;
            float val = 0.f;
            if (h >= 0 && h < HW && wv >= 0 && wv < HW)
                val = x[(((size_t)b * IC + ic0 + icl) * HW + h) * HW + wv];
            xs[icl][hh][ww] = val;
        }
        // stage G: ICB * 4 * OCT * 9 = 2304 elements
        for (int i = tid; i < ICB * 4 * OCT * 9; i += 512) {
            int icl = i / 288;
            int r = i % 288;
            int p = r / 72;
            int r2 = r % 72;
            int o = r2 / 9;
            int kl = r2 % 9;
            gs[icl][p][o][kl] =
                G[(((size_t)(ic0 + icl) * 4 + p) * OC + octile * OCT + o) * 9 + kl];
        }
        __syncthreads();

#pragma unroll 2
        for (int icl = 0; icl < ICB; ++icl) {
            float xr[4][4];
#pragma unroll
            for (int dy = 0; dy < 4; ++dy)
#pragma unroll
                for (int dx = 0; dx < 4; ++dx)
                    xr[dy][dx] = xs[icl][2 * ut + dy][2 * vt + dx];

#pragma unroll
            for (int p = 0; p < 4; ++p) {
#pragma unroll
                for (int k = 0; k < 3; ++k) {
#pragma unroll
                    for (int l = 0; l < 3; ++l) {
                        float g = gs[icl][p][ocl][k * 3 + l];
                        acc[p][0][0] += g * xr[k][l];
                        acc[p][0][1] += g * xr[k][l + 1];
                        acc[p][1][0] += g * xr[k + 1][l];
                        acc[p][1][1] += g * xr[k + 1][l + 1];
                    }
                }
            }
        }
        __syncthreads();
    }

    float bv = bias[oc];
    const float s2 = 1.41421356237309515f;
#pragma unroll
    for (int p = 0; p < 4; ++p) {
        int pm = p >> 1, pn = p & 1;
#pragma unroll
        for (int a = 0; a < 2; ++a) {
#pragma unroll
            for (int c = 0; c < 2; ++c) {
                int u = u0 + 2 * ut + a;
                int v = v0 + 2 * vt + c;
                int m = 2 * u + pm;
                int n = 2 * v + pn;
                float y = acc[p][a][c] + bv;
                y = (y >= 0.f ? y : 0.2f * y) * s2;
                out[(((size_t)b * OC + oc) * OHW + m) * OHW + n] = y;
            }
        }
    }
}

extern "C" void kernel_launch(void* const* d_in, const int* in_sizes, int n_in,
                              void* d_out, int out_size, void* d_ws, size_t ws_size,
                              hipStream_t stream) {
    const float* x    = (const float*)d_in[0];
    const float* w    = (const float*)d_in[1];
    const float* bias = (const float*)d_in[2];
    float* out = (float*)d_out;
    float* G   = (float*)d_ws;   // 18.9 MB needed

    wtrans_kernel<<<(OC * IC + 255) / 256, 256, 0, stream>>>(w, G);

    // grid: 4 spatial tiles * 32 batches * 32 oc-tiles = 4096 blocks
    conv_kernel<<<4096, 512, 0, stream>>>(x, G, bias, out);
}

// Round 3
// 480.975 us; speedup vs baseline: 11.5135x; 11.5135x over previous
//
#include <hip/hip_runtime.h>
#include <hip/hip_bf16.h>
#include <math.h>

// Problem constants
#define B_    32
#define IC    512
#define OC    256
#define HW    32
#define OHW   64

// ws layout:
//   xcl  at offset 0:          bf16 [32][34][34][512]  = 37,879,808 B (zero-padded channels-last)
//   Amat at offset 37,879,808: bf16 [1024][4608]       =  9,437,184 B
//   total 47,316,992 B
#define WS_AMAT_OFF 37879808ull

typedef __attribute__((ext_vector_type(8))) short short8;
typedef __attribute__((ext_vector_type(4))) float f32x4;

#define GPTR(x) ((const __attribute__((address_space(1))) char*)(x))
#define LPTR(x) ((__attribute__((address_space(3))) char*)(x))

// ---------------------------------------------------------------------------
// Weight transform: Amat[(p*256+oc)*4608 + (k*3+l)*512 + ic] =
//   bf16( g2d[2k+1-pm][2l+1-pn] ),  p = pm*2+pn
// g2d[s][t] = sum_{i,j} w[oc,ic,i,j]*gain * f1[s-2+i]*f1[t-2+j]/16 (idx in [0,4))
__global__ __launch_bounds__(256) void wtrans(const float* __restrict__ w,
                                              __hip_bfloat16* __restrict__ Amat) {
    int t = blockIdx.x * blockDim.x + threadIdx.x;  // 131072 threads
    int ic = t & 511, oc = t >> 9;

    const float gain = 1.0f / sqrtf((float)(IC * 9));
    float wl[3][3];
    const float* wp = w + ((size_t)oc * IC + ic) * 9;
#pragma unroll
    for (int i = 0; i < 3; ++i)
#pragma unroll
        for (int j = 0; j < 3; ++j) wl[i][j] = wp[i * 3 + j] * gain;

    const float f1[4] = {1.f, 3.f, 3.f, 1.f};
    float g2[6][6];
#pragma unroll
    for (int s = 0; s < 6; ++s)
#pragma unroll
        for (int tt = 0; tt < 6; ++tt) {
            float acc = 0.f;
#pragma unroll
            for (int i = 0; i < 3; ++i)
#pragma unroll
                for (int j = 0; j < 3; ++j) {
                    int a = s - 2 + i, b = tt - 2 + j;
                    if (a >= 0 && a < 4 && b >= 0 && b < 4)
                        acc += wl[i][j] * f1[a] * f1[b] * 0.0625f;
                }
            g2[s][tt] = acc;
        }

#pragma unroll
    for (int pm = 0; pm < 2; ++pm)
#pragma unroll
        for (int pn = 0; pn < 2; ++pn)
#pragma unroll
            for (int k = 0; k < 3; ++k)
#pragma unroll
                for (int l = 0; l < 3; ++l) {
                    int p = pm * 2 + pn;
                    size_t idx = ((size_t)(p * 256 + oc) * 4608) + (k * 3 + l) * 512 + ic;
                    Amat[idx] = __float2bfloat16(g2[2 * k + 1 - pm][2 * l + 1 - pn]);
                }
}

// ---------------------------------------------------------------------------
// x (fp32 NCHW) -> xcl (bf16, [b][34][34][512], zero halo), via LDS transpose.
__global__ __launch_bounds__(256) void xprep(const float* __restrict__ x,
                                             __hip_bfloat16* __restrict__ xcl) {
    int blk = blockIdx.x;            // 32*34 blocks
    int b = blk / 34, h = blk % 34;
    __hip_bfloat16* orow = xcl + (size_t)(b * 34 + h) * 34 * 512;
    int t = threadIdx.x;
    bool hin = (h >= 1 && h <= 32);

    // halo columns w=0 and w=33
    for (int i = t; i < 2 * 512; i += 256) {
        int wsel = i >> 9, ic = i & 511;
        orow[(size_t)(wsel * 33) * 512 + ic] = __float2bfloat16(0.f);
    }

    __shared__ float ls[16][33];
    int icl_r = t >> 5, wv_r = t & 31;   // load indexing
    int wv_w = t >> 3, icl_w = t & 7;    // store indexing

    for (int ic0 = 0; ic0 < 512; ic0 += 16) {
        __syncthreads();
#pragma unroll
        for (int pp = 0; pp < 2; ++pp) {
            int icll = icl_r + pp * 8;
            float v = 0.f;
            if (hin) v = x[(((size_t)b * IC + ic0 + icll) * HW + (h - 1)) * HW + wv_r];
            ls[icll][wv_r] = v;
        }
        __syncthreads();
#pragma unroll
        for (int pp = 0; pp < 2; ++pp) {
            int icll = icl_w + pp * 8;
            orow[(size_t)(wv_w + 1) * 512 + ic0 + icll] = __float2bfloat16(ls[icll][wv_w]);
        }
    }
}

// ---------------------------------------------------------------------------
// Implicit-GEMM: C[1024][32768] = Amat * B,  B[k=(kl,ic)][n=(b,u,v)] from xcl.
// m97 structure: 128x128 tile, BK=64, 4 waves (2x2), global_load_lds(16B),
// 2-barrier K-loop (72 steps), fused bias + leaky_relu*sqrt(2) epilogue.
__global__ __launch_bounds__(256) void gemm_conv(const __hip_bfloat16* __restrict__ Amat,
                                                 const __hip_bfloat16* __restrict__ xcl,
                                                 const float* __restrict__ bias,
                                                 float* __restrict__ out) {
    __shared__ __align__(1024) char As[128 * 128];  // [row 0..127][64 bf16 = 128B]
    __shared__ __align__(1024) char Bs[128 * 128];

    int bid = blockIdx.x;
    int mt = bid & 7;    // M-tile (8): XCD x gets mt==x -> A-tile L2-resident
    int nt = bid >> 3;   // N-tile (256)
    int tid = threadIdx.x;
    int wid = tid >> 6;
    int lane = tid & 63;

    // staging addresses: round aa covers rows wid*8+(lane>>3)+32*aa
    const char* aptr[4];
    const char* bptr[4];
    char* asl[4];
    char* bsl[4];
#pragma unroll
    for (int aa = 0; aa < 4; ++aa) {
        int row = wid * 8 + (lane >> 3) + 32 * aa;
        aptr[aa] = (const char*)Amat + ((size_t)(mt * 128 + row) * 4608 + (lane & 7) * 8) * 2;
        int n = nt * 128 + row;
        int b = n >> 10, u = (n >> 5) & 31, v = n & 31;
        bptr[aa] = (const char*)xcl + (((size_t)(b * 34 + u) * 34 + v) * 512 + (lane & 7) * 8) * 2;
        asl[aa] = As + (wid * 8 + 32 * aa) * 128;  // + lane*16 implicit in HW
        bsl[aa] = Bs + (wid * 8 + 32 * aa) * 128;
    }

    f32x4 acc[4][4];
#pragma unroll
    for (int mi = 0; mi < 4; ++mi)
#pragma unroll
        for (int ni = 0; ni < 4; ++ni) acc[mi][ni] = (f32x4){0.f, 0.f, 0.f, 0.f};

    int wr = wid >> 1, wc = wid & 1;
    int lr = lane & 15;
    int lkb = (lane >> 4) * 16;  // byte offset of this lane's k-group

    for (int ks = 0; ks < 72; ++ks) {
        int kl = ks >> 3, icc = ks & 7;
        int kh = (kl * 11) >> 5;        // kl/3 for kl in [0,9)
        int kw = kl - 3 * kh;
        size_t aoff = (size_t)ks * 128;
        size_t boff = ((size_t)(kh * 34 + kw) * 512 + icc * 64) * 2;
#pragma unroll
        for (int aa = 0; aa < 4; ++aa) {
            __builtin_amdgcn_global_load_lds(GPTR(aptr[aa] + aoff), LPTR(asl[aa]), 16, 0, 0);
            __builtin_amdgcn_global_load_lds(GPTR(bptr[aa] + boff), LPTR(bsl[aa]), 16, 0, 0);
        }
        __syncthreads();  // compiler drains vmcnt before barrier

        short8 af[2][4], bf[2][4];
#pragma unroll
        for (int ksl = 0; ksl < 2; ++ksl)
#pragma unroll
            for (int i = 0; i < 4; ++i) {
                af[ksl][i] = *(const short8*)(As + (wr * 64 + i * 16 + lr) * 128 + ksl * 64 + lkb);
                bf[ksl][i] = *(const short8*)(Bs + (wc * 64 + i * 16 + lr) * 128 + ksl * 64 + lkb);
            }
#pragma unroll
        for (int ksl = 0; ksl < 2; ++ksl)
#pragma unroll
            for (int mi = 0; mi < 4; ++mi)
#pragma unroll
                for (int ni = 0; ni < 4; ++ni)
                    acc[mi][ni] = __builtin_amdgcn_mfma_f32_16x16x32_bf16(
                        af[ksl][mi], bf[ksl][ni], acc[mi][ni], 0, 0, 0);
        __syncthreads();
    }

    // epilogue: ocp = mt*128 + m_local -> p = mt>>1 (block-uniform), oc = (mt&1)*128 + m_local
    int p = mt >> 1;
    int pm = p >> 1, pn = p & 1;
    const float s2 = 1.41421356237309515f;

#pragma unroll
    for (int mi = 0; mi < 4; ++mi) {
        float bv[4];
#pragma unroll
        for (int r = 0; r < 4; ++r)
            bv[r] = bias[(mt & 1) * 128 + wr * 64 + mi * 16 + (lane >> 4) * 4 + r];
#pragma unroll
        for (int ni = 0; ni < 4; ++ni) {
            int n = nt * 128 + wc * 64 + ni * 16 + lr;
            int b = n >> 10, u = (n >> 5) & 31, v = n & 31;
#pragma unroll
            for (int r = 0; r < 4; ++r) {
                int oc = (mt & 1) * 128 + wr * 64 + mi * 16 + (lane >> 4) * 4 + r;
                float y = acc[mi][ni][r] + bv[r];
                y = (y >= 0.f ? y : 0.2f * y) * s2;
                out[(((size_t)b * OC + oc) * OHW + 2 * u + pm) * OHW + 2 * v + pn] = y;
            }
        }
    }
}

// ---------------------------------------------------------------------------
extern "C" void kernel_launch(void* const* d_in, const int* in_sizes, int n_in,
                              void* d_out, int out_size, void* d_ws, size_t ws_size,
                              hipStream_t stream) {
    const float* x    = (const float*)d_in[0];
    const float* w    = (const float*)d_in[1];
    const float* bias = (const float*)d_in[2];
    float* out = (float*)d_out;

    __hip_bfloat16* xcl  = (__hip_bfloat16*)d_ws;
    __hip_bfloat16* Amat = (__hip_bfloat16*)((char*)d_ws + WS_AMAT_OFF);

    xprep<<<32 * 34, 256, 0, stream>>>(x, xcl);
    wtrans<<<(OC * IC) / 256, 256, 0, stream>>>(w, Amat);
    // grid: 8 M-tiles * 256 N-tiles
    gemm_conv<<<2048, 256, 0, stream>>>(Amat, xcl, bias, out);
}

// Round 4
// 296.304 us; speedup vs baseline: 18.6893x; 1.6232x over previous
//
#include <hip/hip_runtime.h>
#include <hip/hip_bf16.h>
#include <math.h>

// Problem constants
#define B_    32
#define IC    512
#define OC    256
#define HW    32
#define OHW   64

// ws layout:
//   xcl  at offset 0:          bf16 [32][34][34][512]  = 37,879,808 B (zero-padded channels-last)
//   Amat at offset 37,879,808: bf16 [1024][4608]       =  9,437,184 B
#define WS_AMAT_OFF 37879808ull

typedef __attribute__((ext_vector_type(8))) short short8;
typedef __attribute__((ext_vector_type(4))) float f32x4;
typedef __attribute__((ext_vector_type(2))) float f32x2;

#define GPTR(x) ((const __attribute__((address_space(1))) char*)(x))
#define LPTR(x) ((__attribute__((address_space(3))) char*)(x))

// ---------------------------------------------------------------------------
// Weight transform. M-row order is (oc*4 + p) so the GEMM epilogue's 4
// consecutive C-rows per lane are the 4 parities of ONE oc -> coalesced
// 2x2 output quads (fixes the 2x write amplification seen in round 3).
// Amat[(oc*4+p)*4608 + (k*3+l)*512 + ic] = bf16(g2d[2k+1-pm][2l+1-pn])
__global__ __launch_bounds__(256) void wtrans(const float* __restrict__ w,
                                              __hip_bfloat16* __restrict__ Amat) {
    int t = blockIdx.x * blockDim.x + threadIdx.x;  // 131072 threads
    int ic = t & 511, oc = t >> 9;

    const float gain = 1.0f / sqrtf((float)(IC * 9));
    float wl[3][3];
    const float* wp = w + ((size_t)oc * IC + ic) * 9;
#pragma unroll
    for (int i = 0; i < 3; ++i)
#pragma unroll
        for (int j = 0; j < 3; ++j) wl[i][j] = wp[i * 3 + j] * gain;

    const float f1[4] = {1.f, 3.f, 3.f, 1.f};
    float g2[6][6];
#pragma unroll
    for (int s = 0; s < 6; ++s)
#pragma unroll
        for (int tt = 0; tt < 6; ++tt) {
            float acc = 0.f;
#pragma unroll
            for (int i = 0; i < 3; ++i)
#pragma unroll
                for (int j = 0; j < 3; ++j) {
                    int a = s - 2 + i, b = tt - 2 + j;
                    if (a >= 0 && a < 4 && b >= 0 && b < 4)
                        acc += wl[i][j] * f1[a] * f1[b] * 0.0625f;
                }
            g2[s][tt] = acc;
        }

#pragma unroll
    for (int pm = 0; pm < 2; ++pm)
#pragma unroll
        for (int pn = 0; pn < 2; ++pn)
#pragma unroll
            for (int k = 0; k < 3; ++k)
#pragma unroll
                for (int l = 0; l < 3; ++l) {
                    int p = pm * 2 + pn;
                    size_t idx = ((size_t)(oc * 4 + p) * 4608) + (k * 3 + l) * 512 + ic;
                    Amat[idx] = __float2bfloat16(g2[2 * k + 1 - pm][2 * l + 1 - pn]);
                }
}

// ---------------------------------------------------------------------------
// x (fp32 NCHW) -> xcl (bf16, [b][34][34][512], zero halo), via LDS transpose.
__global__ __launch_bounds__(256) void xprep(const float* __restrict__ x,
                                             __hip_bfloat16* __restrict__ xcl) {
    int blk = blockIdx.x;            // 32*34 blocks
    int b = blk / 34, h = blk % 34;
    __hip_bfloat16* orow = xcl + (size_t)(b * 34 + h) * 34 * 512;
    int t = threadIdx.x;
    bool hin = (h >= 1 && h <= 32);

    for (int i = t; i < 2 * 512; i += 256) {
        int wsel = i >> 9, ic = i & 511;
        orow[(size_t)(wsel * 33) * 512 + ic] = __float2bfloat16(0.f);
    }

    __shared__ float ls[16][33];
    int icl_r = t >> 5, wv_r = t & 31;
    int wv_w = t >> 3, icl_w = t & 7;

    for (int ic0 = 0; ic0 < 512; ic0 += 16) {
        __syncthreads();
#pragma unroll
        for (int pp = 0; pp < 2; ++pp) {
            int icll = icl_r + pp * 8;
            float v = 0.f;
            if (hin) v = x[(((size_t)b * IC + ic0 + icll) * HW + (h - 1)) * HW + wv_r];
            ls[icll][wv_r] = v;
        }
        __syncthreads();
#pragma unroll
        for (int pp = 0; pp < 2; ++pp) {
            int icll = icl_w + pp * 8;
            orow[(size_t)(wv_w + 1) * 512 + ic0 + icll] = __float2bfloat16(ls[icll][wv_w]);
        }
    }
}

// ---------------------------------------------------------------------------
// Implicit-GEMM, 256x256 tile, BK=32, 8 waves (2Mx4N), 4-deep LDS ring,
// counted vmcnt(4) pipeline (T3+T4), granule swizzle (T2), setprio (T5).
// C[1024][32768]: M=(oc,p), N=(b,u,v); K = kl*512+ic, NT = 144 K-tiles.
//
// LDS per buffer: A 256x32 bf16 = 16 KB (row=64 B = 4 granules of 16 B),
//                 B same at +16 KB. 4 buffers = 128 KB.
// Swizzle: granule (row, slot) stores global slot (slot ^ ((row>>1)&3)).
//   ds_read lane (q=lane>>4) of row r reads byte r*64 + ((q^f(r))<<4).
//   -> 16-lane frag read covers each 16B-bank-group exactly 2x (free).
__global__ __launch_bounds__(512, 2) void gemm_conv(const __hip_bfloat16* __restrict__ Amat,
                                                    const __hip_bfloat16* __restrict__ xcl,
                                                    const float* __restrict__ bias,
                                                    float* __restrict__ out) {
    __shared__ __align__(1024) char lds[4 * 32768];

    const int NT = 144;
    int bid = blockIdx.x;
    int mt = bid & 3;        // XCD x gets mt = x&3 -> A-tile (2.36 MB) L2-resident
    int nt = bid >> 2;       // 0..127
    int tid = threadIdx.x;
    int wid = tid >> 6;
    int lane = tid & 63;
    int wr = wid >> 2;       // 0..1  (M half)
    int wc = wid & 3;        // 0..3  (N quarter)
    int q = lane >> 4;       // k-granule
    int lr = lane & 15;

    // ---- staging source offsets (thread-fixed; swizzle folded into source) ----
    int rowS = tid >> 2;                 // 0..127 (second load: +128)
    int slt = tid & 3;
    int fS = (rowS >> 1) & 3;            // same for rowS+128
    int sgl = slt ^ fS;                  // global slot fetched into LDS slot slt

    const char* GA = (const char*)Amat + (size_t)mt * 256 * 4608 * 2;
    int offA0 = (rowS * 4608 + sgl * 8) * 2;
    int offA1 = ((rowS + 128) * 4608 + sgl * 8) * 2;

    int n0 = nt * 256 + rowS;
    int b0 = n0 >> 10, u0 = (n0 >> 5) & 31, v0 = n0 & 31;
    int n1 = n0 + 128;
    int b1 = n1 >> 10, u1 = (n1 >> 5) & 31, v1 = n1 & 31;
    const char* GB = (const char*)xcl;
    int offB0 = ((b0 * 34 + u0) * 34 + v0) * 1024 + sgl * 16;
    int offB1 = ((b1 * 34 + u1) * 34 + v1) * 1024 + sgl * 16;

    int dA0 = wid * 1024;                // + lane*16 added by HW
    int dA1 = 8192 + wid * 1024;
    int dB0 = 16384 + wid * 1024;
    int dB1 = 16384 + 8192 + wid * 1024;

    // ---- ds_read offsets (thread-fixed, swizzled) ----
    int aoffs[8], boffs[4];
#pragma unroll
    for (int mi = 0; mi < 8; ++mi) {
        int r = wr * 128 + mi * 16 + lr;
        aoffs[mi] = r * 64 + ((q ^ ((r >> 1) & 3)) << 4);
    }
#pragma unroll
    for (int ni = 0; ni < 4; ++ni) {
        int r = wc * 64 + ni * 16 + lr;
        boffs[ni] = 16384 + r * 64 + ((q ^ ((r >> 1) & 3)) << 4);
    }

    f32x4 acc[8][4];
#pragma unroll
    for (int mi = 0; mi < 8; ++mi)
#pragma unroll
        for (int ni = 0; ni < 4; ++ni) acc[mi][ni] = (f32x4){0.f, 0.f, 0.f, 0.f};

    // stage K-tile ks into ring buffer bufi (4 global_load_lds per thread)
    auto STAGE = [&](int ks, int bufi) {
        int kl = ks >> 4;
        int kh = (kl * 11) >> 5;         // kl/3 for kl in [0,9)
        int kw = kl - 3 * kh;
        int bko = (kh * 34 + kw) * 1024 + (ks & 15) * 64;
        int ao = ks * 64;
        char* L = lds + bufi * 32768;
        __builtin_amdgcn_global_load_lds(GPTR(GA + offA0 + ao), LPTR(L + dA0), 16, 0, 0);
        __builtin_amdgcn_global_load_lds(GPTR(GA + offA1 + ao), LPTR(L + dA1), 16, 0, 0);
        __builtin_amdgcn_global_load_lds(GPTR(GB + offB0 + bko), LPTR(L + dB0), 16, 0, 0);
        __builtin_amdgcn_global_load_lds(GPTR(GB + offB1 + bko), LPTR(L + dB1), 16, 0, 0);
    };

    // prologue: fill pipeline depth 2
    STAGE(0, 0);
    STAGE(1, 1);

    for (int t = 0; t < NT; ++t) {
        // counted wait: outstanding <= 8 (t, t+1); keep t+1's 4 in flight
        asm volatile("s_waitcnt vmcnt(4)" ::: "memory");
        __builtin_amdgcn_s_barrier();
        __builtin_amdgcn_sched_barrier(0);

        int kp = t + 2 < NT ? t + 2 : NT - 1;   // clamp: keeps vmcnt math exact
        STAGE(kp, (t + 2) & 3);

        const char* Lc = lds + (t & 3) * 32768;
        short8 af[8], bf[4];
#pragma unroll
        for (int mi = 0; mi < 8; ++mi) af[mi] = *(const short8*)(Lc + aoffs[mi]);
#pragma unroll
        for (int ni = 0; ni < 4; ++ni) bf[ni] = *(const short8*)(Lc + boffs[ni]);

        __builtin_amdgcn_s_setprio(1);
#pragma unroll
        for (int mi = 0; mi < 8; ++mi)
#pragma unroll
            for (int ni = 0; ni < 4; ++ni)
                acc[mi][ni] = __builtin_amdgcn_mfma_f32_16x16x32_bf16(
                    af[mi], bf[ni], acc[mi][ni], 0, 0, 0);
        __builtin_amdgcn_s_setprio(0);
    }
    // drain before epilogue (outstanding gload_lds must not outlive the block)
    asm volatile("s_waitcnt vmcnt(0)" ::: "memory");

    // ---- epilogue: 4 acc regs per frag = 4 parities of one oc -> 2x2 quad ----
    const float s2 = 1.41421356237309515f;
#pragma unroll
    for (int mi = 0; mi < 8; ++mi) {
        int oc = mt * 64 + wr * 32 + mi * 4 + q;
        float bv = bias[oc];
#pragma unroll
        for (int ni = 0; ni < 4; ++ni) {
            int n = nt * 256 + wc * 64 + ni * 16 + lr;
            int b = n >> 10, u = (n >> 5) & 31, v = n & 31;
            float y0 = acc[mi][ni][0] + bv;
            float y1 = acc[mi][ni][1] + bv;
            float y2 = acc[mi][ni][2] + bv;
            float y3 = acc[mi][ni][3] + bv;
            y0 = (y0 >= 0.f ? y0 : 0.2f * y0) * s2;
            y1 = (y1 >= 0.f ? y1 : 0.2f * y1) * s2;
            y2 = (y2 >= 0.f ? y2 : 0.2f * y2) * s2;
            y3 = (y3 >= 0.f ? y3 : 0.2f * y3) * s2;
            size_t base = (((size_t)b * OC + oc) * OHW + 2 * u) * OHW + 2 * v;
            *(f32x2*)(out + base)       = (f32x2){y0, y1};   // row 2u:   p=(0,0),(0,1)
            *(f32x2*)(out + base + OHW) = (f32x2){y2, y3};   // row 2u+1: p=(1,0),(1,1)
        }
    }
}

// ---------------------------------------------------------------------------
extern "C" void kernel_launch(void* const* d_in, const int* in_sizes, int n_in,
                              void* d_out, int out_size, void* d_ws, size_t ws_size,
                              hipStream_t stream) {
    const float* x    = (const float*)d_in[0];
    const float* w    = (const float*)d_in[1];
    const float* bias = (const float*)d_in[2];
    float* out = (float*)d_out;

    __hip_bfloat16* xcl  = (__hip_bfloat16*)d_ws;
    __hip_bfloat16* Amat = (__hip_bfloat16*)((char*)d_ws + WS_AMAT_OFF);

    xprep<<<32 * 34, 256, 0, stream>>>(x, xcl);
    wtrans<<<(OC * IC) / 256, 256, 0, stream>>>(w, Amat);
    // grid: 4 M-tiles * 128 N-tiles = 512 blocks, 512 threads
    gemm_conv<<<512, 512, 0, stream>>>(Amat, xcl, bias, out);
}

// Round 5
// 293.568 us; speedup vs baseline: 18.8635x; 1.0093x over previous
//
#include <hip/hip_runtime.h>
#include <hip/hip_bf16.h>
#include <math.h>

// Problem constants
#define B_    32
#define IC    512
#define OC    256
#define HW    32
#define OHW   64

// ws layout:
//   xcl  at offset 0:          bf16 [32][34][34][512]  = 37,879,808 B (zero-padded channels-last)
//   Amat at offset 37,879,808: bf16 [1024][4608]       =  9,437,184 B
#define WS_AMAT_OFF 37879808ull

typedef __attribute__((ext_vector_type(8))) short short8;
typedef __attribute__((ext_vector_type(4))) float f32x4;
typedef __attribute__((ext_vector_type(2))) float f32x2;

#define GPTR(x) ((const __attribute__((address_space(1))) char*)(x))
#define LPTR(x) ((__attribute__((address_space(3))) char*)(x))

// ---------------------------------------------------------------------------
// Weight transform. M-row order (oc*4 + p): 4 consecutive C-rows per lane are
// the 4 parities of one oc -> coalesced 2x2 output quads in the epilogue.
__global__ __launch_bounds__(256) void wtrans(const float* __restrict__ w,
                                              __hip_bfloat16* __restrict__ Amat) {
    int t = blockIdx.x * blockDim.x + threadIdx.x;  // 131072 threads
    int ic = t & 511, oc = t >> 9;

    const float gain = 1.0f / sqrtf((float)(IC * 9));
    float wl[3][3];
    const float* wp = w + ((size_t)oc * IC + ic) * 9;
#pragma unroll
    for (int i = 0; i < 3; ++i)
#pragma unroll
        for (int j = 0; j < 3; ++j) wl[i][j] = wp[i * 3 + j] * gain;

    const float f1[4] = {1.f, 3.f, 3.f, 1.f};
    float g2[6][6];
#pragma unroll
    for (int s = 0; s < 6; ++s)
#pragma unroll
        for (int tt = 0; tt < 6; ++tt) {
            float acc = 0.f;
#pragma unroll
            for (int i = 0; i < 3; ++i)
#pragma unroll
                for (int j = 0; j < 3; ++j) {
                    int a = s - 2 + i, b = tt - 2 + j;
                    if (a >= 0 && a < 4 && b >= 0 && b < 4)
                        acc += wl[i][j] * f1[a] * f1[b] * 0.0625f;
                }
            g2[s][tt] = acc;
        }

#pragma unroll
    for (int pm = 0; pm < 2; ++pm)
#pragma unroll
        for (int pn = 0; pn < 2; ++pn)
#pragma unroll
            for (int k = 0; k < 3; ++k)
#pragma unroll
                for (int l = 0; l < 3; ++l) {
                    int p = pm * 2 + pn;
                    size_t idx = ((size_t)(oc * 4 + p) * 4608) + (k * 3 + l) * 512 + ic;
                    Amat[idx] = __float2bfloat16(g2[2 * k + 1 - pm][2 * l + 1 - pn]);
                }
}

// ---------------------------------------------------------------------------
// x (fp32 NCHW) -> xcl (bf16, [b][34][34][512], zero halo), via LDS transpose.
__global__ __launch_bounds__(256) void xprep(const float* __restrict__ x,
                                             __hip_bfloat16* __restrict__ xcl) {
    int blk = blockIdx.x;            // 32*34 blocks
    int b = blk / 34, h = blk % 34;
    __hip_bfloat16* orow = xcl + (size_t)(b * 34 + h) * 34 * 512;
    int t = threadIdx.x;
    bool hin = (h >= 1 && h <= 32);

    for (int i = t; i < 2 * 512; i += 256) {
        int wsel = i >> 9, ic = i & 511;
        orow[(size_t)(wsel * 33) * 512 + ic] = __float2bfloat16(0.f);
    }

    __shared__ float ls[16][33];
    int icl_r = t >> 5, wv_r = t & 31;
    int wv_w = t >> 3, icl_w = t & 7;

    for (int ic0 = 0; ic0 < 512; ic0 += 16) {
        __syncthreads();
#pragma unroll
        for (int pp = 0; pp < 2; ++pp) {
            int icll = icl_r + pp * 8;
            float v = 0.f;
            if (hin) v = x[(((size_t)b * IC + ic0 + icll) * HW + (h - 1)) * HW + wv_r];
            ls[icll][wv_r] = v;
        }
        __syncthreads();
#pragma unroll
        for (int pp = 0; pp < 2; ++pp) {
            int icll = icl_w + pp * 8;
            orow[(size_t)(wv_w + 1) * 512 + ic0 + icll] = __float2bfloat16(ls[icll][wv_w]);
        }
    }
}

// ---------------------------------------------------------------------------
// Implicit-GEMM, 256x256 tile, BK=32, 8 waves (2Mx4N), 4-deep LDS ring,
// counted vmcnt(4) (T4), granule swizzle (T2, conflicts=0 verified),
// setprio (T5), and NEW: register double-buffered fragments so the 12
// ds_read_b128 of tile t+1 overlap the 32 MFMA of tile t (phase overlap).
//
// Race safety (ring-4, distance-2): reads of tile t-2 retired (lgkmcnt
// before MFMA(t-2), which precedes barrier B(t-1)); STAGE(t+2) writes that
// buffer only after B(t) -> >= 2 barriers separation.
__global__ __launch_bounds__(512, 2) void gemm_conv(const __hip_bfloat16* __restrict__ Amat,
                                                    const __hip_bfloat16* __restrict__ xcl,
                                                    const float* __restrict__ bias,
                                                    float* __restrict__ out) {
    __shared__ __align__(1024) char lds[4 * 32768];

    const int NT = 144;
    int bid = blockIdx.x;
    int mt = bid & 3;        // XCD x gets mt = x&3 -> A-tile (2.36 MB) L2-resident
    int nt = bid >> 2;       // 0..127
    int tid = threadIdx.x;
    int wid = tid >> 6;
    int lane = tid & 63;
    int wr = wid >> 2;       // 0..1  (M half)
    int wc = wid & 3;        // 0..3  (N quarter)
    int q = lane >> 4;       // k-granule
    int lr = lane & 15;

    // ---- staging source offsets (swizzle folded into global source) ----
    int rowS = tid >> 2;                 // 0..127 (second load: +128)
    int slt = tid & 3;
    int fS = (rowS >> 1) & 3;
    int sgl = slt ^ fS;                  // global slot fetched into LDS slot slt

    const char* GA = (const char*)Amat + (size_t)mt * 256 * 4608 * 2;
    int offA0 = (rowS * 4608 + sgl * 8) * 2;
    int offA1 = ((rowS + 128) * 4608 + sgl * 8) * 2;

    int n0 = nt * 256 + rowS;
    int b0i = n0 >> 10, u0 = (n0 >> 5) & 31, v0 = n0 & 31;
    int n1 = n0 + 128;
    int b1i = n1 >> 10, u1 = (n1 >> 5) & 31, v1 = n1 & 31;
    const char* GB = (const char*)xcl;
    int offB0 = ((b0i * 34 + u0) * 34 + v0) * 1024 + sgl * 16;
    int offB1 = ((b1i * 34 + u1) * 34 + v1) * 1024 + sgl * 16;

    int dA0 = wid * 1024;                // + lane*16 added by HW
    int dA1 = 8192 + wid * 1024;
    int dB0 = 16384 + wid * 1024;
    int dB1 = 16384 + 8192 + wid * 1024;

    // ---- ds_read bases (swizzle s = (lr>>1)&3 is mi/ni-independent) ----
    int qs = (q ^ ((lr >> 1) & 3)) << 4;
    int A0 = (wr * 128 + lr) * 64 + qs;           // + mi*1024 as imm
    int B0 = 16384 + (wc * 64 + lr) * 64 + qs;    // + ni*1024 as imm

    f32x4 acc[8][4];
#pragma unroll
    for (int mi = 0; mi < 8; ++mi)
#pragma unroll
        for (int ni = 0; ni < 4; ++ni) acc[mi][ni] = (f32x4){0.f, 0.f, 0.f, 0.f};

    auto STAGE = [&](int ks, int bufi) {
        int kl = ks >> 4;
        int kh = (kl * 11) >> 5;         // kl/3 for kl in [0,9)
        int kw = kl - 3 * kh;
        int bko = (kh * 34 + kw) * 1024 + (ks & 15) * 64;
        int ao = ks * 64;
        char* L = lds + bufi * 32768;
        __builtin_amdgcn_global_load_lds(GPTR(GA + offA0 + ao), LPTR(L + dA0), 16, 0, 0);
        __builtin_amdgcn_global_load_lds(GPTR(GA + offA1 + ao), LPTR(L + dA1), 16, 0, 0);
        __builtin_amdgcn_global_load_lds(GPTR(GB + offB0 + bko), LPTR(L + dB0), 16, 0, 0);
        __builtin_amdgcn_global_load_lds(GPTR(GB + offB1 + bko), LPTR(L + dB1), 16, 0, 0);
    };

    short8 a0[8], b0[4], a1[8], b1[4];

    // prologue: fill pipeline depth 2, load tile 0's fragments
    STAGE(0, 0);
    STAGE(1, 1);
    asm volatile("s_waitcnt vmcnt(4)" ::: "memory");   // tile 0 landed
    __builtin_amdgcn_s_barrier();
    __builtin_amdgcn_sched_barrier(0);
    {
        const char* L = lds;  // buf 0
#pragma unroll
        for (int mi = 0; mi < 8; ++mi) a0[mi] = *(const short8*)(L + A0 + mi * 1024);
#pragma unroll
        for (int ni = 0; ni < 4; ++ni) b0[ni] = *(const short8*)(L + B0 + ni * 1024);
    }

    for (int t = 0; t < NT; t += 2) {
        // ---- half 1: prefetch tile t+1 -> set1, MFMA tile t (set0) ----
        STAGE(t + 2 < NT ? t + 2 : NT - 1, (t + 2) & 3);
        asm volatile("s_waitcnt vmcnt(4)" ::: "memory");   // tile t+1 landed
        __builtin_amdgcn_s_barrier();
        __builtin_amdgcn_sched_barrier(0);
        {
            const char* L = lds + ((t + 1) & 3) * 32768;
#pragma unroll
            for (int mi = 0; mi < 8; ++mi) a1[mi] = *(const short8*)(L + A0 + mi * 1024);
#pragma unroll
            for (int ni = 0; ni < 4; ++ni) b1[ni] = *(const short8*)(L + B0 + ni * 1024);
        }
        __builtin_amdgcn_sched_barrier(0);  // keep read issue ahead of MFMA cluster
        __builtin_amdgcn_s_setprio(1);
#pragma unroll
        for (int mi = 0; mi < 8; ++mi)
#pragma unroll
            for (int ni = 0; ni < 4; ++ni)
                acc[mi][ni] = __builtin_amdgcn_mfma_f32_16x16x32_bf16(
                    a0[mi], b0[ni], acc[mi][ni], 0, 0, 0);
        __builtin_amdgcn_s_setprio(0);

        // ---- half 2: prefetch tile t+2 -> set0, MFMA tile t+1 (set1) ----
        STAGE(t + 3 < NT ? t + 3 : NT - 1, (t + 3) & 3);
        asm volatile("s_waitcnt vmcnt(4)" ::: "memory");   // tile t+2 landed
        __builtin_amdgcn_s_barrier();
        __builtin_amdgcn_sched_barrier(0);
        {
            const char* L = lds + ((t + 2) & 3) * 32768;
#pragma unroll
            for (int mi = 0; mi < 8; ++mi) a0[mi] = *(const short8*)(L + A0 + mi * 1024);
#pragma unroll
            for (int ni = 0; ni < 4; ++ni) b0[ni] = *(const short8*)(L + B0 + ni * 1024);
        }
        __builtin_amdgcn_sched_barrier(0);
        __builtin_amdgcn_s_setprio(1);
#pragma unroll
        for (int mi = 0; mi < 8; ++mi)
#pragma unroll
            for (int ni = 0; ni < 4; ++ni)
                acc[mi][ni] = __builtin_amdgcn_mfma_f32_16x16x32_bf16(
                    a1[mi], b1[ni], acc[mi][ni], 0, 0, 0);
        __builtin_amdgcn_s_setprio(0);
    }
    asm volatile("s_waitcnt vmcnt(0)" ::: "memory");   // drain clamped stages

    // ---- epilogue: 4 acc regs per frag = 4 parities of one oc -> 2x2 quad ----
    const float s2 = 1.41421356237309515f;
#pragma unroll
    for (int mi = 0; mi < 8; ++mi) {
        int oc = mt * 64 + wr * 32 + mi * 4 + q;
        float bv = bias[oc];
#pragma unroll
        for (int ni = 0; ni < 4; ++ni) {
            int n = nt * 256 + wc * 64 + ni * 16 + lr;
            int b = n >> 10, u = (n >> 5) & 31, v = n & 31;
            float y0 = acc[mi][ni][0] + bv;
            float y1 = acc[mi][ni][1] + bv;
            float y2 = acc[mi][ni][2] + bv;
            float y3 = acc[mi][ni][3] + bv;
            y0 = (y0 >= 0.f ? y0 : 0.2f * y0) * s2;
            y1 = (y1 >= 0.f ? y1 : 0.2f * y1) * s2;
            y2 = (y2 >= 0.f ? y2 : 0.2f * y2) * s2;
            y3 = (y3 >= 0.f ? y3 : 0.2f * y3) * s2;
            size_t base = (((size_t)b * OC + oc) * OHW + 2 * u) * OHW + 2 * v;
            *(f32x2*)(out + base)       = (f32x2){y0, y1};   // row 2u:   p=(0,0),(0,1)
            *(f32x2*)(out + base + OHW) = (f32x2){y2, y3};   // row 2u+1: p=(1,0),(1,1)
        }
    }
}

// ---------------------------------------------------------------------------
extern "C" void kernel_launch(void* const* d_in, const int* in_sizes, int n_in,
                              void* d_out, int out_size, void* d_ws, size_t ws_size,
                              hipStream_t stream) {
    const float* x    = (const float*)d_in[0];
    const float* w    = (const float*)d_in[1];
    const float* bias = (const float*)d_in[2];
    float* out = (float*)d_out;

    __hip_bfloat16* xcl  = (__hip_bfloat16*)d_ws;
    __hip_bfloat16* Amat = (__hip_bfloat16*)((char*)d_ws + WS_AMAT_OFF);

    xprep<<<32 * 34, 256, 0, stream>>>(x, xcl);
    wtrans<<<(OC * IC) / 256, 256, 0, stream>>>(w, Amat);
    // grid: 4 M-tiles * 128 N-tiles = 512 blocks, 512 threads
    gemm_conv<<<512, 512, 0, stream>>>(Amat, xcl, bias, out);
}